// Round 11
// baseline (383.804 us; speedup 1.0000x reference)
//
#include <hip/hip_runtime.h>

// VQ-VAE VectorQuantizer: B=32, C=D=64, H=W=64, K=512
// d_in[0]: inputs  [32,64,64,64] f32 (NCHW, C = embedding dim)
// d_in[1]: embedding [512,64] f32
// d_out: [loss(1) | out(32*64*64*64) | indices(32*4096)] all read as f32
//
// V11 = round-5's 203us configuration (best measured) with its ONE measured
// pathology fixed: vq_full was 129us at VGPR=256 / occupancy 0.01% (LDS-
// pointer exact_u + unrolled shfl -> worst-case allocation on a do-nothing
// kernel). Replaced with a lean thread-per-listed-position full scan
// (thread-local x[64], non-unrolled k-loop, no LDS, no shfl: the round-0
// kernel shape, VGPR ~100). Screen (top-3 + atomic g3 list) and writer
// (1 thread/pos, 56us measured) are byte-identical to round 5. Prep merged
// into one launch (R7b-proven).
// Correctness (round-5-proven, passed): screen error on score differences
// <= ~1e-4 < DELTA=2.5e-4; candidates {i1,i2} cover argmin unless g3
// escalates (-> vq_full exact 512-scan; overflow -> writer inline scan).
// Exact path = round-0-proven fmaf/pairwise-8 ordering; first-min kept.

#define KCODE 512
#define EMB   64
#define HWSZ  4096
#define NPOS  131072
#define DELTA 2.5e-4f

typedef short short8  __attribute__((ext_vector_type(8)));
typedef float float4v __attribute__((ext_vector_type(4)));

// ws float layout (round-5):
//   [0] fullCnt (uint)   [1] writer ticket (uint)   [2..7] pad
//   [8..519]    writer block partials (512)
//   [520..1031] e2 (numpy rounding, by code)
//   [1032..33799] bfrag short8[32][2][2][64] (128 KB)
//   [33800..]   g3 full-scan list (cap from ws_size, <=1024)

// ---------- numpy-exact helpers ----------
__device__ __forceinline__ float np_sumsq64(const float* a) {
    #pragma clang fp contract(off)
    {
        float r0 = a[0] * a[0], r1 = a[1] * a[1], r2 = a[2] * a[2], r3 = a[3] * a[3];
        float r4 = a[4] * a[4], r5 = a[5] * a[5], r6 = a[6] * a[6], r7 = a[7] * a[7];
        for (int i = 8; i < 64; i += 8) {
            r0 += a[i + 0] * a[i + 0];
            r1 += a[i + 1] * a[i + 1];
            r2 += a[i + 2] * a[i + 2];
            r3 += a[i + 3] * a[i + 3];
            r4 += a[i + 4] * a[i + 4];
            r5 += a[i + 5] * a[i + 5];
            r6 += a[i + 6] * a[i + 6];
            r7 += a[i + 7] * a[i + 7];
        }
        return ((r0 + r1) + (r2 + r3)) + ((r4 + r5) + (r6 + r7));
    }
}

// exact numpy distance: u = fl(fl(x2 - 2*xe) + e2k)  (round-0-proven order)
__device__ __forceinline__ float exact_u(const float* x, float x2,
                                         const float* ek, float e2k) {
    float t0 = 0.f, t1 = 0.f, t2 = 0.f, t3 = 0.f;
    #pragma unroll
    for (int c = 0; c < EMB; c += 4) {
        t0 = fmaf(x[c + 0], ek[c + 0], t0);
        t1 = fmaf(x[c + 1], ek[c + 1], t1);
        t2 = fmaf(x[c + 2], ek[c + 2], t2);
        t3 = fmaf(x[c + 3], ek[c + 3], t3);
    }
    float xe  = (t0 + t1) + (t2 + t3);
    float tmp = x2 - 2.0f * xe;     // 2*xe exact -> contraction rounding-identical
    return tmp + e2k;
}

__device__ __forceinline__ unsigned short bf16rne(float f) {
    unsigned u = __float_as_uint(f);
    unsigned r = (u + 0x7FFFu + ((u >> 16) & 1u)) >> 16;
    return (unsigned short)r;
}
__device__ __forceinline__ float bf16tof(unsigned short h) {
    return __uint_as_float((unsigned)h << 16);
}

// sorted-insert of (v,i) into ((M1,I1),(M2,I2),M3); strict < keeps earlier.
#define INS(M1, I1, M2, I2, M3, v, i)                      \
    {                                                      \
        bool lt1 = (v) < (M1), lt2 = (v) < (M2), lt3 = (v) < (M3); \
        (M3) = lt2 ? (M2) : (lt3 ? (v) : (M3));            \
        (I2) = lt1 ? (I1) : (lt2 ? (i) : (I2));            \
        (M2) = lt1 ? (M1) : (lt2 ? (v) : (M2));            \
        (M1) = lt1 ? (v) : (M1);                           \
        (I1) = lt1 ? (i) : (I1);                           \
    }

// ---------- prep: e2 + bfrag + counter zeroing (merged, R7b-proven) -------
__global__ void vq_prep(const float* __restrict__ emb, float* __restrict__ ws) {
    int f = blockIdx.x * blockDim.x + threadIdx.x;   // 0..4095
    if (f == 0) { ((unsigned*)ws)[0] = 0u; ((unsigned*)ws)[1] = 0u; }
    if (f < KCODE) ws[520 + f] = np_sumsq64(emb + f * EMB);
    short8* bfrag = (short8*)(ws + 1032);
    int l = f & 63;
    int c = (f >> 6) & 1;
    int t = f >> 7;            // 0..31
    int code  = t * 16 + (l & 15);
    int dbase = 32 * c + ((l >> 4) & 3) * 8;
    const float* e = emb + code * EMB + dbase;
    short8 h, lo;
    #pragma unroll
    for (int j = 0; j < 8; ++j) {
        float v = e[j];
        unsigned short hb = bf16rne(v);
        float hf = bf16tof(hb);
        unsigned short lb = bf16rne(v - hf);
        h[j]  = (short)hb;
        lo[j] = (short)lb;
    }
    bfrag[t * 256 + c * 128 + 0 * 64 + l] = h;
    bfrag[t * 256 + c * 128 + 1 * 64 + l] = lo;
}

// ---------- screen: single MFMA sweep, top-3 tracking (round-5 verbatim) --
__global__ __launch_bounds__(256, 3) void vq_screen(
        const float*  __restrict__ in,
        const float*  __restrict__ e2np,      // ws+520
        const short8* __restrict__ bfrag,     // ws+1032
        float*        __restrict__ out_idx,   // packed {i1,i2,g2,g3}
        unsigned*     __restrict__ fullCnt,   // ws+0
        unsigned*     __restrict__ fullList,  // ws+33800
        int fullCap) {
    const int tid  = threadIdx.x;
    const int wave = tid >> 6;
    const int lane = tid & 63;
    const int lg   = lane >> 4;
    const int lc   = lane & 15;
    const int wavePos = blockIdx.x * 128 + wave * 32;

    // A-fragments: 2 pos-tiles x 2 dim-chunks, hi/lo of g = -2x.
    // A element j of lane: row = lane&15 (position), k-dim = (lane>>4)*8+j.
    short8 fH[2][2], fL[2][2];
    #pragma unroll
    for (int pt = 0; pt < 2; ++pt) {
        int pos = wavePos + pt * 16 + lc;
        int b   = pos >> 12;
        int hw  = pos & (HWSZ - 1);
        const float* xb = in + ((size_t)b << 18) + hw;
        #pragma unroll
        for (int c = 0; c < 2; ++c) {
            short8 h, lo;
            #pragma unroll
            for (int j = 0; j < 8; ++j) {
                int d = 32 * c + lg * 8 + j;
                float g = -2.0f * xb[(size_t)d << 12];
                unsigned short hb = bf16rne(g);
                float hf = bf16tof(hb);
                unsigned short lb = bf16rne(g - hf);
                h[j]  = (short)hb;
                lo[j] = (short)lb;
            }
            fH[pt][c] = h;
            fL[pt][c] = lo;
        }
    }

    float m1[2][4], m2[2][4], m3[2][4];
    int   i1[2][4], i2[2][4];
    #pragma unroll
    for (int pt = 0; pt < 2; ++pt)
        #pragma unroll
        for (int r = 0; r < 4; ++r) {
            m1[pt][r] = 3.4e38f; m2[pt][r] = 3.4e38f; m3[pt][r] = 3.4e38f;
            i1[pt][r] = 0;       i2[pt][r] = 0;
        }

    // t-loop with register prefetch of next B tile (4x b128 + e2)
    short8 ceh0 = bfrag[lane],       cel0 = bfrag[64 + lane];
    short8 ceh1 = bfrag[128 + lane], cel1 = bfrag[192 + lane];
    float  ce2  = e2np[lc];
    #pragma unroll 2
    for (int t = 0; t < 32; ++t) {
        short8 neh0, nel0, neh1, nel1;
        float  ne2 = 0.0f;
        if (t < 31) {
            const short8* nb = bfrag + (t + 1) * 256;
            neh0 = nb[lane];       nel0 = nb[64 + lane];
            neh1 = nb[128 + lane]; nel1 = nb[192 + lane];
            ne2  = e2np[(t + 1) * 16 + lc];
        }
        const int kf = t * 16 + lc;
        #pragma unroll
        for (int pt = 0; pt < 2; ++pt) {
            float4v aH = {ce2, ce2, ce2, ce2};
            float4v aM = {0.f, 0.f, 0.f, 0.f};
            float4v aL = {0.f, 0.f, 0.f, 0.f};
            aH = __builtin_amdgcn_mfma_f32_16x16x32_bf16(fH[pt][0], ceh0, aH, 0, 0, 0);
            aM = __builtin_amdgcn_mfma_f32_16x16x32_bf16(fH[pt][0], cel0, aM, 0, 0, 0);
            aL = __builtin_amdgcn_mfma_f32_16x16x32_bf16(fL[pt][0], ceh0, aL, 0, 0, 0);
            aH = __builtin_amdgcn_mfma_f32_16x16x32_bf16(fH[pt][1], ceh1, aH, 0, 0, 0);
            aM = __builtin_amdgcn_mfma_f32_16x16x32_bf16(fH[pt][1], cel1, aM, 0, 0, 0);
            aL = __builtin_amdgcn_mfma_f32_16x16x32_bf16(fL[pt][1], ceh1, aL, 0, 0, 0);
            #pragma unroll
            for (int r = 0; r < 4; ++r) {
                float sv = (aH[r] + aM[r]) + aL[r];
                INS(m1[pt][r], i1[pt][r], m2[pt][r], i2[pt][r], m3[pt][r], sv, kf);
            }
        }
        ceh0 = neh0; cel0 = nel0; ceh1 = neh1; cel1 = nel1; ce2 = ne2;
    }

    // cross-lane top-3 merge over the 16-lane code group
    #pragma unroll
    for (int pt = 0; pt < 2; ++pt) {
        #pragma unroll
        for (int r = 0; r < 4; ++r) {
            float M1 = m1[pt][r], M2 = m2[pt][r], M3 = m3[pt][r];
            int   I1 = i1[pt][r], I2 = i2[pt][r];
            #pragma unroll
            for (int d = 1; d <= 8; d <<= 1) {
                float pm1 = __shfl_xor(M1, d, 64);
                int   pi1 = __shfl_xor(I1, d, 64);
                float pm2 = __shfl_xor(M2, d, 64);
                int   pi2 = __shfl_xor(I2, d, 64);
                float pm3 = __shfl_xor(M3, d, 64);
                INS(M1, I1, M2, I2, M3, pm1, pi1);
                INS(M1, I1, M2, I2, M3, pm2, pi2);
                M3 = fminf(M3, pm3);    // pm3 >= pm2 >= post-insert M2
            }
            m1[pt][r] = M1; m2[pt][r] = M2; m3[pt][r] = M3;
            i1[pt][r] = I1; i2[pt][r] = I2;
        }
    }

    if (lc == 0) {
        #pragma unroll
        for (int pt = 0; pt < 2; ++pt) {
            #pragma unroll
            for (int r = 0; r < 4; ++r) {
                int p  = wavePos + pt * 16 + lg * 4 + r;
                int g2 = (m2[pt][r] - m1[pt][r] <= DELTA) ? 1 : 0;
                int g3 = (m3[pt][r] - m1[pt][r] <= DELTA) ? 1 : 0;
                int packed = i1[pt][r] | (i2[pt][r] << 9) | (g2 << 18) | (g3 << 19);
                out_idx[p] = (float)packed;   // < 2^20: exact in fp32
                if (g3) {
                    unsigned slot = atomicAdd(fullCnt, 1u);
                    if (slot < (unsigned)fullCap) fullList[slot] = (unsigned)p;
                }
            }
        }
    }
}

// ---------- lean full-scan: THREAD per listed position (V11 fix) ----------
// Round-5's version was wave-per-entry with LDS x + unrolled shfl: VGPR=256,
// occupancy 0.01%, 129us while doing ~nothing. This shape is the round-0
// kernel's (thread-local x[64], plain k-loop): VGPR ~100, no LDS, no shfl.
__global__ __launch_bounds__(64) void vq_full(
        const float* __restrict__ in, const float* __restrict__ emb,
        const float* __restrict__ e2np, const unsigned* __restrict__ fullCnt,
        const unsigned* __restrict__ fullList, int fullCap,
        float* __restrict__ out_idx) {
    unsigned cnt = *fullCnt;
    if (cnt > (unsigned)fullCap) cnt = (unsigned)fullCap;
    unsigned idx = blockIdx.x * 64 + threadIdx.x;
    if (idx >= cnt) return;
    const int n  = (int)fullList[idx];
    const int b  = n >> 12;
    const int hw = n & (HWSZ - 1);
    const float* xp = in + ((size_t)b << 18) + hw;
    float x[EMB];
    #pragma unroll
    for (int c = 0; c < EMB; ++c) x[c] = xp[(size_t)c << 12];
    const float x2 = np_sumsq64(x);
    float bu = 3.4e38f;
    int   bk = 0;
    for (int k = 0; k < KCODE; ++k) {          // ascending + strict <: first min
        float u = exact_u(x, x2, emb + k * EMB, e2np[k]);
        if (u < bu) { bu = u; bk = k; }
    }
    out_idx[n] = (float)bk;                    // plain index, flags cleared
}

// ---------- writer: round-5 verbatim (measured 56us) ----------------------
__global__ __launch_bounds__(256) void vq_write(
        const float* __restrict__ in, const float* __restrict__ emb,
        const float* __restrict__ e2np,
        float* __restrict__ out_idx, float* __restrict__ out_q,
        float* __restrict__ partials,           // ws+8, [512]
        unsigned* __restrict__ ticket,          // ws+1
        float* __restrict__ out_loss) {
    const int tid = threadIdx.x;
    const int n   = blockIdx.x * 256 + tid;
    const int b   = n >> 12;
    const int hw  = n & (HWSZ - 1);

    const float* xp = in + ((size_t)b << 18) + hw;
    float x[EMB];
    #pragma unroll
    for (int c = 0; c < EMB; ++c) x[c] = xp[(size_t)c << 12];

    int v = (int)out_idx[n];
    int k = v & 511;
    int fl = v >> 18;
    if (fl) {
        float x2 = np_sumsq64(x);
        if (fl & 2) {
            // unlisted g3 overflow (statistically never): exact full scan
            float bu = 3.4e38f; int bk = 0;
            for (int kk = 0; kk < KCODE; ++kk) {
                float u = exact_u(x, x2, emb + kk * EMB, e2np[kk]);
                if (u < bu) { bu = u; bk = kk; }
            }
            k = bk;
        } else {
            int ia = v & 511, ib = (v >> 9) & 511;
            float u1 = exact_u(x, x2, emb + ia * EMB, e2np[ia]);
            float u2 = exact_u(x, x2, emb + ib * EMB, e2np[ib]);
            k = (u1 < u2) ? ia : (u2 < u1 ? ib : (ia < ib ? ia : ib));
        }
    }
    out_idx[n] = (float)k;

    const float4* qk = (const float4*)(emb + (size_t)k * EMB);
    float* op = out_q + ((size_t)b << 18) + hw;
    float s = 0.0f;
    #pragma unroll
    for (int c4 = 0; c4 < EMB / 4; ++c4) {
        float4 q = qk[c4];
        float d0 = q.x - x[c4 * 4 + 0];
        float d1 = q.y - x[c4 * 4 + 1];
        float d2 = q.z - x[c4 * 4 + 2];
        float d3 = q.w - x[c4 * 4 + 3];
        s = fmaf(d0, d0, s); s = fmaf(d1, d1, s);
        s = fmaf(d2, d2, s); s = fmaf(d3, d3, s);
        op[(size_t)(c4 * 4 + 0) << 12] = q.x;
        op[(size_t)(c4 * 4 + 1) << 12] = q.y;
        op[(size_t)(c4 * 4 + 2) << 12] = q.z;
        op[(size_t)(c4 * 4 + 3) << 12] = q.w;
    }

    // deterministic loss: wave shuffle -> LDS -> block partial -> ticket
    #pragma unroll
    for (int off = 32; off > 0; off >>= 1)
        s += __shfl_down(s, off, 64);
    __shared__ float red[4];
    const int wave = tid >> 6;
    const int lane = tid & 63;
    if (lane == 0) red[wave] = s;
    __syncthreads();
    if (tid == 0) {
        partials[blockIdx.x] = (red[0] + red[1]) + (red[2] + red[3]);
        __threadfence();
        unsigned tk = atomicAdd(ticket, 1u);
        if (tk == 511u) {
            __threadfence();
            float a0 = 0.f, a1 = 0.f, a2 = 0.f, a3 = 0.f;
            float a4 = 0.f, a5 = 0.f, a6 = 0.f, a7 = 0.f;
            for (int i = 0; i < 512; i += 8) {
                a0 += partials[i + 0]; a1 += partials[i + 1];
                a2 += partials[i + 2]; a3 += partials[i + 3];
                a4 += partials[i + 4]; a5 += partials[i + 5];
                a6 += partials[i + 6]; a7 += partials[i + 7];
            }
            float tot = ((a0 + a1) + (a2 + a3)) + ((a4 + a5) + (a6 + a7));
            out_loss[0] = 1.25f * tot * (1.0f / ((float)NPOS * (float)EMB));
        }
    }
}

extern "C" void kernel_launch(void* const* d_in, const int* in_sizes, int n_in,
                              void* d_out, int out_size, void* d_ws, size_t ws_size,
                              hipStream_t stream) {
    const float* in  = (const float*)d_in[0];
    const float* emb = (const float*)d_in[1];
    float* ws  = (float*)d_ws;
    float* out = (float*)d_out;

    float*    out_loss = out;
    float*    out_q    = out + 1;
    float*    out_idx  = out + 1 + (size_t)NPOS * EMB;
    unsigned* fullCnt  = (unsigned*)ws;          // ws[0]
    unsigned* ticket   = (unsigned*)ws + 1;      // ws[1]
    float*    partials = ws + 8;                 // [512]
    float*    e2np     = ws + 520;               // [512]
    short8*   bfrag    = (short8*)(ws + 1032);   // 128 KB
    unsigned* fullList = (unsigned*)(ws + 33800);

    // g3 list capacity limited by what the workspace provably holds
    long avail = (long)(ws_size / 4) - 33800;
    int  fullCap = avail > 0 ? (avail > 1024 ? 1024 : (int)avail) : 0;

    vq_prep<<<16, 256, 0, stream>>>(emb, ws);
    vq_screen<<<NPOS / 128, 256, 0, stream>>>(in, e2np, bfrag, out_idx,
                                              fullCnt, fullList, fullCap);
    vq_full<<<16, 64, 0, stream>>>(in, emb, e2np, fullCnt, fullList, fullCap,
                                   out_idx);
    vq_write<<<NPOS / 256, 256, 0, stream>>>(in, emb, e2np, out_idx, out_q,
                                             partials, ticket, out_loss);
}

// Round 12
// 183.558 us; speedup vs baseline: 2.0909x; 2.0909x over previous
//
#include <hip/hip_runtime.h>

// VQ-VAE VectorQuantizer: B=32, C=D=64, H=W=64, K=512
// d_in[0]: inputs  [32,64,64,64] f32 (NCHW, C = embedding dim)
// d_in[1]: embedding [512,64] f32
// d_out: [loss(1) | out(32*64*64*64) | indices(32*4096)] all read as f32
//
// V13: the session's key invariant, finally isolated (R0/R10/R11 evidence):
// ONE thread serially scanning 512 codes = ~500k cycles of dependent L2
// latency = ~200us wall time, regardless of VGPR or occupancy. R11's lean
// thread-per-entry vq_full (VGPR 44!) still measured 218us. Round 5's writer
// was 56us only because its inline-scan branch never executed; R10's 195us
// writer was g4-flagged threads running that scan.
// Fix: vq_full is WAVE-PARALLEL - one wave per listed position, 8 codes per
// lane (serial depth 8), x staged via LDS (block = 1 wave -> __syncthreads
// is a legal wave barrier), loop-based (no unrolled shfl monsters, no
// pointer selects), lexicographic (u,k) reduce. ~2-4us per entry, ~260
// entries over 256 blocks.
// Screen (R5 top-3 MFMA sweep) and writer (R5 verbatim, 56us measured)
// unchanged.
// Correctness: screen error on score differences <= ~1e-4 < DELTA=2.5e-4;
// {i1,i2} cover numpy's argmin unless g3 escalates (-> vq_full exact scan;
// list cap 1024 >> observed ~260; overflow -> writer inline scan, never
// executed in practice but exact). Exact path = round-0-proven
// fmaf/pairwise-8 ordering; first-min semantics throughout.

#define KCODE 512
#define EMB   64
#define HWSZ  4096
#define NPOS  131072
#define DELTA 2.5e-4f

typedef short short8  __attribute__((ext_vector_type(8)));
typedef float float4v __attribute__((ext_vector_type(4)));

// ws float layout:
//   [0] fullCnt (uint)   [1] writer ticket (uint)   [2..7] pad
//   [8..519]    writer block partials (512)
//   [520..1031] e2 (numpy rounding, by code)
//   [1032..33799] bfrag short8[32][2][2][64] (128 KB)
//   [33800..]   g3 full-scan list (cap from ws_size, <=1024)

// ---------- numpy-exact helpers ----------
__device__ __forceinline__ float np_sumsq64(const float* a) {
    #pragma clang fp contract(off)
    {
        float r0 = a[0] * a[0], r1 = a[1] * a[1], r2 = a[2] * a[2], r3 = a[3] * a[3];
        float r4 = a[4] * a[4], r5 = a[5] * a[5], r6 = a[6] * a[6], r7 = a[7] * a[7];
        for (int i = 8; i < 64; i += 8) {
            r0 += a[i + 0] * a[i + 0];
            r1 += a[i + 1] * a[i + 1];
            r2 += a[i + 2] * a[i + 2];
            r3 += a[i + 3] * a[i + 3];
            r4 += a[i + 4] * a[i + 4];
            r5 += a[i + 5] * a[i + 5];
            r6 += a[i + 6] * a[i + 6];
            r7 += a[i + 7] * a[i + 7];
        }
        return ((r0 + r1) + (r2 + r3)) + ((r4 + r5) + (r6 + r7));
    }
}

// exact numpy distance: u = fl(fl(x2 - 2*xe) + e2k)  (round-0-proven order)
__device__ __forceinline__ float exact_u(const float* x, float x2,
                                         const float* ek, float e2k) {
    float t0 = 0.f, t1 = 0.f, t2 = 0.f, t3 = 0.f;
    #pragma unroll
    for (int c = 0; c < EMB; c += 4) {
        t0 = fmaf(x[c + 0], ek[c + 0], t0);
        t1 = fmaf(x[c + 1], ek[c + 1], t1);
        t2 = fmaf(x[c + 2], ek[c + 2], t2);
        t3 = fmaf(x[c + 3], ek[c + 3], t3);
    }
    float xe  = (t0 + t1) + (t2 + t3);
    float tmp = x2 - 2.0f * xe;     // 2*xe exact -> contraction rounding-identical
    return tmp + e2k;
}

__device__ __forceinline__ unsigned short bf16rne(float f) {
    unsigned u = __float_as_uint(f);
    unsigned r = (u + 0x7FFFu + ((u >> 16) & 1u)) >> 16;
    return (unsigned short)r;
}
__device__ __forceinline__ float bf16tof(unsigned short h) {
    return __uint_as_float((unsigned)h << 16);
}

// sorted-insert of (v,i) into ((M1,I1),(M2,I2),M3); strict < keeps earlier.
#define INS(M1, I1, M2, I2, M3, v, i)                      \
    {                                                      \
        bool lt1 = (v) < (M1), lt2 = (v) < (M2), lt3 = (v) < (M3); \
        (M3) = lt2 ? (M2) : (lt3 ? (v) : (M3));            \
        (I2) = lt1 ? (I1) : (lt2 ? (i) : (I2));            \
        (M2) = lt1 ? (M1) : (lt2 ? (v) : (M2));            \
        (M1) = lt1 ? (v) : (M1);                           \
        (I1) = lt1 ? (i) : (I1);                           \
    }

// ---------- prep: e2 + bfrag + counter zeroing ----------
__global__ void vq_prep(const float* __restrict__ emb, float* __restrict__ ws) {
    int f = blockIdx.x * blockDim.x + threadIdx.x;   // 0..4095
    if (f == 0) { ((unsigned*)ws)[0] = 0u; ((unsigned*)ws)[1] = 0u; }
    if (f < KCODE) ws[520 + f] = np_sumsq64(emb + f * EMB);
    short8* bfrag = (short8*)(ws + 1032);
    int l = f & 63;
    int c = (f >> 6) & 1;
    int t = f >> 7;            // 0..31
    int code  = t * 16 + (l & 15);
    int dbase = 32 * c + ((l >> 4) & 3) * 8;
    const float* e = emb + code * EMB + dbase;
    short8 h, lo;
    #pragma unroll
    for (int j = 0; j < 8; ++j) {
        float v = e[j];
        unsigned short hb = bf16rne(v);
        float hf = bf16tof(hb);
        unsigned short lb = bf16rne(v - hf);
        h[j]  = (short)hb;
        lo[j] = (short)lb;
    }
    bfrag[t * 256 + c * 128 + 0 * 64 + l] = h;
    bfrag[t * 256 + c * 128 + 1 * 64 + l] = lo;
}

// ---------- screen: single MFMA sweep, top-3 tracking (R5 verbatim) -------
__global__ __launch_bounds__(256, 3) void vq_screen(
        const float*  __restrict__ in,
        const float*  __restrict__ e2np,      // ws+520
        const short8* __restrict__ bfrag,     // ws+1032
        float*        __restrict__ out_idx,   // packed {i1,i2,g2,g3}
        unsigned*     __restrict__ fullCnt,   // ws+0
        unsigned*     __restrict__ fullList,  // ws+33800
        int fullCap) {
    const int tid  = threadIdx.x;
    const int wave = tid >> 6;
    const int lane = tid & 63;
    const int lg   = lane >> 4;
    const int lc   = lane & 15;
    const int wavePos = blockIdx.x * 128 + wave * 32;

    // A-fragments: 2 pos-tiles x 2 dim-chunks, hi/lo of g = -2x.
    short8 fH[2][2], fL[2][2];
    #pragma unroll
    for (int pt = 0; pt < 2; ++pt) {
        int pos = wavePos + pt * 16 + lc;
        int b   = pos >> 12;
        int hw  = pos & (HWSZ - 1);
        const float* xb = in + ((size_t)b << 18) + hw;
        #pragma unroll
        for (int c = 0; c < 2; ++c) {
            short8 h, lo;
            #pragma unroll
            for (int j = 0; j < 8; ++j) {
                int d = 32 * c + lg * 8 + j;
                float g = -2.0f * xb[(size_t)d << 12];
                unsigned short hb = bf16rne(g);
                float hf = bf16tof(hb);
                unsigned short lb = bf16rne(g - hf);
                h[j]  = (short)hb;
                lo[j] = (short)lb;
            }
            fH[pt][c] = h;
            fL[pt][c] = lo;
        }
    }

    float m1[2][4], m2[2][4], m3[2][4];
    int   i1[2][4], i2[2][4];
    #pragma unroll
    for (int pt = 0; pt < 2; ++pt)
        #pragma unroll
        for (int r = 0; r < 4; ++r) {
            m1[pt][r] = 3.4e38f; m2[pt][r] = 3.4e38f; m3[pt][r] = 3.4e38f;
            i1[pt][r] = 0;       i2[pt][r] = 0;
        }

    short8 ceh0 = bfrag[lane],       cel0 = bfrag[64 + lane];
    short8 ceh1 = bfrag[128 + lane], cel1 = bfrag[192 + lane];
    float  ce2  = e2np[lc];
    #pragma unroll 2
    for (int t = 0; t < 32; ++t) {
        short8 neh0, nel0, neh1, nel1;
        float  ne2 = 0.0f;
        if (t < 31) {
            const short8* nb = bfrag + (t + 1) * 256;
            neh0 = nb[lane];       nel0 = nb[64 + lane];
            neh1 = nb[128 + lane]; nel1 = nb[192 + lane];
            ne2  = e2np[(t + 1) * 16 + lc];
        }
        const int kf = t * 16 + lc;
        #pragma unroll
        for (int pt = 0; pt < 2; ++pt) {
            float4v aH = {ce2, ce2, ce2, ce2};
            float4v aM = {0.f, 0.f, 0.f, 0.f};
            float4v aL = {0.f, 0.f, 0.f, 0.f};
            aH = __builtin_amdgcn_mfma_f32_16x16x32_bf16(fH[pt][0], ceh0, aH, 0, 0, 0);
            aM = __builtin_amdgcn_mfma_f32_16x16x32_bf16(fH[pt][0], cel0, aM, 0, 0, 0);
            aL = __builtin_amdgcn_mfma_f32_16x16x32_bf16(fL[pt][0], ceh0, aL, 0, 0, 0);
            aH = __builtin_amdgcn_mfma_f32_16x16x32_bf16(fH[pt][1], ceh1, aH, 0, 0, 0);
            aM = __builtin_amdgcn_mfma_f32_16x16x32_bf16(fH[pt][1], cel1, aM, 0, 0, 0);
            aL = __builtin_amdgcn_mfma_f32_16x16x32_bf16(fL[pt][1], ceh1, aL, 0, 0, 0);
            #pragma unroll
            for (int r = 0; r < 4; ++r) {
                float sv = (aH[r] + aM[r]) + aL[r];
                INS(m1[pt][r], i1[pt][r], m2[pt][r], i2[pt][r], m3[pt][r], sv, kf);
            }
        }
        ceh0 = neh0; cel0 = nel0; ceh1 = neh1; cel1 = nel1; ce2 = ne2;
    }

    // cross-lane top-3 merge over the 16-lane code group
    #pragma unroll
    for (int pt = 0; pt < 2; ++pt) {
        #pragma unroll
        for (int r = 0; r < 4; ++r) {
            float M1 = m1[pt][r], M2 = m2[pt][r], M3 = m3[pt][r];
            int   I1 = i1[pt][r], I2 = i2[pt][r];
            #pragma unroll
            for (int d = 1; d <= 8; d <<= 1) {
                float pm1 = __shfl_xor(M1, d, 64);
                int   pi1 = __shfl_xor(I1, d, 64);
                float pm2 = __shfl_xor(M2, d, 64);
                int   pi2 = __shfl_xor(I2, d, 64);
                float pm3 = __shfl_xor(M3, d, 64);
                INS(M1, I1, M2, I2, M3, pm1, pi1);
                INS(M1, I1, M2, I2, M3, pm2, pi2);
                M3 = fminf(M3, pm3);    // pm3 >= pm2 >= post-insert M2
            }
            m1[pt][r] = M1; m2[pt][r] = M2; m3[pt][r] = M3;
            i1[pt][r] = I1; i2[pt][r] = I2;
        }
    }

    if (lc == 0) {
        #pragma unroll
        for (int pt = 0; pt < 2; ++pt) {
            #pragma unroll
            for (int r = 0; r < 4; ++r) {
                int p  = wavePos + pt * 16 + lg * 4 + r;
                int g2 = (m2[pt][r] - m1[pt][r] <= DELTA) ? 1 : 0;
                int g3 = (m3[pt][r] - m1[pt][r] <= DELTA) ? 1 : 0;
                int packed = i1[pt][r] | (i2[pt][r] << 9) | (g2 << 18) | (g3 << 19);
                out_idx[p] = (float)packed;   // < 2^20: exact in fp32
                if (g3) {
                    unsigned slot = atomicAdd(fullCnt, 1u);
                    if (slot < (unsigned)fullCap) fullList[slot] = (unsigned)p;
                }
            }
        }
    }
}

// ---------- full-scan: WAVE per listed position, 8 codes/lane (V13) -------
// Serial depth per thread = 8 code evaluations (not 512). x staged via LDS;
// block = 1 wave so __syncthreads() is a cheap legal wave barrier. All loops
// kept loop-based to avoid fat-path register allocation.
__global__ __launch_bounds__(64) void vq_full(
        const float* __restrict__ in, const float* __restrict__ emb,
        const float* __restrict__ e2np, const unsigned* __restrict__ fullCnt,
        const unsigned* __restrict__ fullList, int fullCap,
        float* __restrict__ out_idx) {
    __shared__ float xbuf[EMB];
    const int lane = threadIdx.x;
    unsigned cnt = *fullCnt;
    if (cnt > (unsigned)fullCap) cnt = (unsigned)fullCap;

    for (unsigned idx = blockIdx.x; idx < cnt; idx += gridDim.x) {
        const int n  = (int)fullList[idx];
        const int b  = n >> 12;
        const int hw = n & (HWSZ - 1);
        // stage x: lane l loads dim l
        xbuf[lane] = in[((size_t)b << 18) + ((size_t)lane << 12) + hw];
        __syncthreads();

        // x2 from LDS, numpy pairwise-8 order (loop-based, 8 named accums)
        float x2;
        {
            #pragma clang fp contract(off)
            float r0 = xbuf[0] * xbuf[0], r1 = xbuf[1] * xbuf[1];
            float r2 = xbuf[2] * xbuf[2], r3 = xbuf[3] * xbuf[3];
            float r4 = xbuf[4] * xbuf[4], r5 = xbuf[5] * xbuf[5];
            float r6 = xbuf[6] * xbuf[6], r7 = xbuf[7] * xbuf[7];
            #pragma unroll 1
            for (int i = 8; i < EMB; i += 8) {
                r0 += xbuf[i + 0] * xbuf[i + 0];
                r1 += xbuf[i + 1] * xbuf[i + 1];
                r2 += xbuf[i + 2] * xbuf[i + 2];
                r3 += xbuf[i + 3] * xbuf[i + 3];
                r4 += xbuf[i + 4] * xbuf[i + 4];
                r5 += xbuf[i + 5] * xbuf[i + 5];
                r6 += xbuf[i + 6] * xbuf[i + 6];
                r7 += xbuf[i + 7] * xbuf[i + 7];
            }
            x2 = ((r0 + r1) + (r2 + r3)) + ((r4 + r5) + (r6 + r7));
        }

        // 8 codes per lane: k = j*64 + lane (loop-based, NOT unrolled)
        float bu = 3.4e38f;
        int   bk = 0x7fffffff;
        #pragma unroll 1
        for (int j = 0; j < 8; ++j) {
            const int k = j * 64 + lane;
            const float* ek = emb + (size_t)k * EMB;
            float t0 = 0.f, t1 = 0.f, t2 = 0.f, t3 = 0.f;
            #pragma unroll 4
            for (int c = 0; c < EMB; c += 4) {
                t0 = fmaf(xbuf[c + 0], ek[c + 0], t0);
                t1 = fmaf(xbuf[c + 1], ek[c + 1], t1);
                t2 = fmaf(xbuf[c + 2], ek[c + 2], t2);
                t3 = fmaf(xbuf[c + 3], ek[c + 3], t3);
            }
            float xe  = (t0 + t1) + (t2 + t3);
            float tmp = x2 - 2.0f * xe;
            float u   = tmp + e2np[k];
            if (u < bu || (u == bu && k < bk)) { bu = u; bk = k; }
        }
        // lexicographic (u,k) wave reduce == numpy first-min
        #pragma unroll
        for (int d = 1; d < 64; d <<= 1) {
            float ou = __shfl_xor(bu, d, 64);
            int   ok = __shfl_xor(bk, d, 64);
            if (ou < bu || (ou == bu && ok < bk)) { bu = ou; bk = ok; }
        }
        if (lane == 0) out_idx[n] = (float)bk;   // plain index, flags cleared
        __syncthreads();   // xbuf safe to overwrite next iteration
    }
}

// ---------- writer: R5 verbatim (measured 56us) ---------------------------
__global__ __launch_bounds__(256) void vq_write(
        const float* __restrict__ in, const float* __restrict__ emb,
        const float* __restrict__ e2np,
        float* __restrict__ out_idx, float* __restrict__ out_q,
        float* __restrict__ partials,           // ws+8, [512]
        unsigned* __restrict__ ticket,          // ws+1
        float* __restrict__ out_loss) {
    const int tid = threadIdx.x;
    const int n   = blockIdx.x * 256 + tid;
    const int b   = n >> 12;
    const int hw  = n & (HWSZ - 1);

    const float* xp = in + ((size_t)b << 18) + hw;
    float x[EMB];
    #pragma unroll
    for (int c = 0; c < EMB; ++c) x[c] = xp[(size_t)c << 12];

    int v = (int)out_idx[n];
    int k = v & 511;
    int fl = v >> 18;
    if (fl) {
        float x2 = np_sumsq64(x);
        if (fl & 2) {
            // unlisted g3 overflow (never in practice: cap 1024 >> ~260)
            float bu = 3.4e38f; int bk = 0;
            for (int kk = 0; kk < KCODE; ++kk) {
                float u = exact_u(x, x2, emb + kk * EMB, e2np[kk]);
                if (u < bu) { bu = u; bk = kk; }
            }
            k = bk;
        } else {
            int ia = v & 511, ib = (v >> 9) & 511;
            float u1 = exact_u(x, x2, emb + ia * EMB, e2np[ia]);
            float u2 = exact_u(x, x2, emb + ib * EMB, e2np[ib]);
            k = (u1 < u2) ? ia : (u2 < u1 ? ib : (ia < ib ? ia : ib));
        }
    }
    out_idx[n] = (float)k;

    const float4* qk = (const float4*)(emb + (size_t)k * EMB);
    float* op = out_q + ((size_t)b << 18) + hw;
    float s = 0.0f;
    #pragma unroll
    for (int c4 = 0; c4 < EMB / 4; ++c4) {
        float4 q = qk[c4];
        float d0 = q.x - x[c4 * 4 + 0];
        float d1 = q.y - x[c4 * 4 + 1];
        float d2 = q.z - x[c4 * 4 + 2];
        float d3 = q.w - x[c4 * 4 + 3];
        s = fmaf(d0, d0, s); s = fmaf(d1, d1, s);
        s = fmaf(d2, d2, s); s = fmaf(d3, d3, s);
        op[(size_t)(c4 * 4 + 0) << 12] = q.x;
        op[(size_t)(c4 * 4 + 1) << 12] = q.y;
        op[(size_t)(c4 * 4 + 2) << 12] = q.z;
        op[(size_t)(c4 * 4 + 3) << 12] = q.w;
    }

    // deterministic loss: wave shuffle -> LDS -> block partial -> ticket
    #pragma unroll
    for (int off = 32; off > 0; off >>= 1)
        s += __shfl_down(s, off, 64);
    __shared__ float red[4];
    const int wave = tid >> 6;
    const int lane = tid & 63;
    if (lane == 0) red[wave] = s;
    __syncthreads();
    if (tid == 0) {
        partials[blockIdx.x] = (red[0] + red[1]) + (red[2] + red[3]);
        __threadfence();
        unsigned tk = atomicAdd(ticket, 1u);
        if (tk == 511u) {
            __threadfence();
            float a0 = 0.f, a1 = 0.f, a2 = 0.f, a3 = 0.f;
            float a4 = 0.f, a5 = 0.f, a6 = 0.f, a7 = 0.f;
            for (int i = 0; i < 512; i += 8) {
                a0 += partials[i + 0]; a1 += partials[i + 1];
                a2 += partials[i + 2]; a3 += partials[i + 3];
                a4 += partials[i + 4]; a5 += partials[i + 5];
                a6 += partials[i + 6]; a7 += partials[i + 7];
            }
            float tot = ((a0 + a1) + (a2 + a3)) + ((a4 + a5) + (a6 + a7));
            out_loss[0] = 1.25f * tot * (1.0f / ((float)NPOS * (float)EMB));
        }
    }
}

extern "C" void kernel_launch(void* const* d_in, const int* in_sizes, int n_in,
                              void* d_out, int out_size, void* d_ws, size_t ws_size,
                              hipStream_t stream) {
    const float* in  = (const float*)d_in[0];
    const float* emb = (const float*)d_in[1];
    float* ws  = (float*)d_ws;
    float* out = (float*)d_out;

    float*    out_loss = out;
    float*    out_q    = out + 1;
    float*    out_idx  = out + 1 + (size_t)NPOS * EMB;
    unsigned* fullCnt  = (unsigned*)ws;          // ws[0]
    unsigned* ticket   = (unsigned*)ws + 1;      // ws[1]
    float*    partials = ws + 8;                 // [512]
    float*    e2np     = ws + 520;               // [512]
    short8*   bfrag    = (short8*)(ws + 1032);   // 128 KB
    unsigned* fullList = (unsigned*)(ws + 33800);

    // g3 list capacity limited by what the workspace provably holds
    long avail = (long)(ws_size / 4) - 33800;
    int  fullCap = avail > 0 ? (avail > 1024 ? 1024 : (int)avail) : 0;

    vq_prep<<<16, 256, 0, stream>>>(emb, ws);
    vq_screen<<<NPOS / 128, 256, 0, stream>>>(in, e2np, bfrag, out_idx,
                                              fullCnt, fullList, fullCap);
    vq_full<<<256, 64, 0, stream>>>(in, emb, e2np, fullCnt, fullList, fullCap,
                                    out_idx);
    vq_write<<<NPOS / 256, 256, 0, stream>>>(in, emb, e2np, out_idx, out_q,
                                             partials, ticket, out_loss);
}